// Round 3
// baseline (73.655 us; speedup 1.0000x reference)
//
#include <hip/hip_runtime.h>

typedef float v2f __attribute__((ext_vector_type(2)));

constexpr int WIDTH  = 96;
constexpr int HEIGHT = 72;
constexpr int NPTS   = WIDTH * HEIGHT;   // 6912
constexpr int BLOCK  = 128;              // threads per block (2 waves)
constexpr int NTILE  = 256;              // n-points per block (2 per thread)
constexpr int MTILE  = 64;               // m-points per block
constexpr int NTB    = NPTS / NTILE;     // 27
constexpr int MTB    = NPTS / MTILE;     // 108
constexpr int NBLK   = NTB * MTB;        // 2916

// exp(-0.1*d) = exp2(d * KEXP)
constexpr float KEXP  = -0.14426950408889634f;  // -0.1 * log2(e)
constexpr float M2K   = -2.0f * KEXP;           // scale for a-side geometry

// Per-point layout (b-side / LDS form):
//  0..2  xyz1         3  K*|xyz1|^2
//  4..6  xyz2_t       7  K*|xyz2_t|^2
//  8..10 xyz2_gt     11  K*|xyz2_gt|^2
// 12..14 f1          15..17 f2
__device__ __forceinline__ void point_data(
    int idx,
    const float* __restrict__ depth1, const float* __restrict__ depth2,
    const float* __restrict__ img1,   const float* __restrict__ img2,
    const float R[12], const float G[12], float o[18])
{
    const int u = idx % WIDTH;
    const int v = idx / WIDTH;
    const float gy = (float)u * (1.0f / 48.0f) - 1.0f;
    const float gz = (float)v * (1.0f / 36.0f) - 1.0f;
    const float d1 = depth1[idx];
    const float d2 = depth2[idx];
    const float x1 = d1, y1 = d1 * gy, z1 = d1 * gz;
    const float x2 = d2, y2 = d2 * gy, z2 = d2 * gz;
    const float xt = R[0] * x2 + R[1] * y2 + R[2]  * z2 + R[3];
    const float yt = R[4] * x2 + R[5] * y2 + R[6]  * z2 + R[7];
    const float zt = R[8] * x2 + R[9] * y2 + R[10] * z2 + R[11];
    const float xg = G[0] * x2 + G[1] * y2 + G[2]  * z2 + G[3];
    const float yg = G[4] * x2 + G[5] * y2 + G[6]  * z2 + G[7];
    const float zg = G[8] * x2 + G[9] * y2 + G[10] * z2 + G[11];

    o[0] = x1; o[1] = y1; o[2]  = z1; o[3]  = KEXP * (x1*x1 + y1*y1 + z1*z1);
    o[4] = xt; o[5] = yt; o[6]  = zt; o[7]  = KEXP * (xt*xt + yt*yt + zt*zt);
    o[8] = xg; o[9] = yg; o[10] = zg; o[11] = KEXP * (xg*xg + yg*yg + zg*zg);
    o[12] = img1[idx];
    o[13] = img1[NPTS + idx];
    o[14] = img1[2 * NPTS + idx];
    o[15] = img2[idx];
    o[16] = img2[NPTS + idx];
    o[17] = img2[2 * NPTS + idx];
}

__global__ __launch_bounds__(BLOCK, 5) void pair_kernel(
    const float* __restrict__ depth1, const float* __restrict__ depth2,
    const float* __restrict__ pose,   const float* __restrict__ img1,
    const float* __restrict__ img2,   const float* __restrict__ poseg,
    float* __restrict__ partials)
{
    __shared__ float sm[MTILE][20];    // 80B rows
    __shared__ float red[2][5];

    const int t  = threadIdx.x;
    const int bn = blockIdx.x % NTB;
    const int bm = blockIdx.x / NTB;

    float R[12], G[12];
#pragma unroll
    for (int i = 0; i < 12; ++i) { R[i] = pose[i]; G[i] = poseg[i]; }

    // stage m-tile into LDS (threads 0..MTILE-1)
    if (t < MTILE) {
        float o[18];
        point_data(bm * MTILE + t, depth1, depth2, img1, img2, R, G, o);
#pragma unroll
        for (int k = 0; k < 18; ++k) sm[t][k] = o[k];
    }

    // two n-points per thread, packed as v2f; a-side geometry pre-scaled by -2K
    v2f A[18];
    {
        float o0[18], o1[18];
        point_data(bn * NTILE + t,         depth1, depth2, img1, img2, R, G, o0);
        point_data(bn * NTILE + BLOCK + t, depth1, depth2, img1, img2, R, G, o1);
#pragma unroll
        for (int k = 0; k < 18; ++k) { A[k].x = o0[k]; A[k].y = o1[k]; }
#pragma unroll
        for (int grp = 0; grp < 3; ++grp) {
#pragma unroll
            for (int k = 0; k < 3; ++k) A[grp * 4 + k] *= M2K;
        }
    }

    __syncthreads();

    v2f s0 = {0.f, 0.f}, s1 = s0, s2 = s0, s3 = s0, s4 = s0;

#define COMPUTE(b)                                                         \
    do {                                                                   \
        v2f t11 = A[3] + (b)[3];                                           \
        t11 = A[0] * (b)[0] + t11;                                         \
        t11 = A[1] * (b)[1] + t11;                                         \
        t11 = A[2] * (b)[2] + t11;                                         \
        v2f t22 = A[7] + (b)[7];                                           \
        t22 = A[4] * (b)[4] + t22;                                         \
        t22 = A[5] * (b)[5] + t22;                                         \
        t22 = A[6] * (b)[6] + t22;                                         \
        v2f t12 = A[3] + (b)[7];                                           \
        t12 = A[0] * (b)[4] + t12;                                         \
        t12 = A[1] * (b)[5] + t12;                                         \
        t12 = A[2] * (b)[6] + t12;                                         \
        v2f tgg = A[11] + (b)[11];                                         \
        tgg = A[8]  * (b)[8]  + tgg;                                       \
        tgg = A[9]  * (b)[9]  + tgg;                                       \
        tgg = A[10] * (b)[10] + tgg;                                       \
        v2f t1g = A[3] + (b)[11];                                          \
        t1g = A[0] * (b)[8]  + t1g;                                        \
        t1g = A[1] * (b)[9]  + t1g;                                        \
        t1g = A[2] * (b)[10] + t1g;                                        \
        v2f g11 = A[12] * (b)[12];                                         \
        g11 = A[13] * (b)[13] + g11;                                       \
        g11 = A[14] * (b)[14] + g11;                                       \
        v2f g22 = A[15] * (b)[15];                                         \
        g22 = A[16] * (b)[16] + g22;                                       \
        g22 = A[17] * (b)[17] + g22;                                       \
        v2f g12 = A[12] * (b)[15];                                         \
        g12 = A[13] * (b)[16] + g12;                                       \
        g12 = A[14] * (b)[17] + g12;                                       \
        v2f e11, e22, e12, egg, e1g;                                       \
        e11.x = __builtin_amdgcn_exp2f(t11.x);                             \
        e11.y = __builtin_amdgcn_exp2f(t11.y);                             \
        e22.x = __builtin_amdgcn_exp2f(t22.x);                             \
        e22.y = __builtin_amdgcn_exp2f(t22.y);                             \
        e12.x = __builtin_amdgcn_exp2f(t12.x);                             \
        e12.y = __builtin_amdgcn_exp2f(t12.y);                             \
        egg.x = __builtin_amdgcn_exp2f(tgg.x);                             \
        egg.y = __builtin_amdgcn_exp2f(tgg.y);                             \
        e1g.x = __builtin_amdgcn_exp2f(t1g.x);                             \
        e1g.y = __builtin_amdgcn_exp2f(t1g.y);                             \
        s0 = e11 * g11 + s0;                                               \
        s1 = e22 * g22 + s1;                                               \
        s2 = e12 * g12 + s2;                                               \
        s3 = egg * g22 + s3;                                               \
        s4 = e1g * g12 + s4;                                               \
    } while (0)

    // 2-deep register pipeline over the m-tile
    float b0[18], b1[18];
#pragma unroll
    for (int k = 0; k < 18; ++k) b0[k] = sm[0][k];

    for (int m = 0; m < MTILE; m += 2) {
#pragma unroll
        for (int k = 0; k < 18; ++k) b1[k] = sm[m + 1][k];
        COMPUTE(b0);
#pragma unroll
        for (int k = 0; k < 18; ++k) b0[k] = sm[(m + 2) & (MTILE - 1)][k];
        COMPUTE(b1);
    }
#undef COMPUTE

    // per-thread fold then 64-lane reduction
    float r0 = s0.x + s0.y, r1 = s1.x + s1.y, r2 = s2.x + s2.y,
          r3 = s3.x + s3.y, r4 = s4.x + s4.y;
#pragma unroll
    for (int off = 32; off > 0; off >>= 1) {
        r0 += __shfl_down(r0, off);
        r1 += __shfl_down(r1, off);
        r2 += __shfl_down(r2, off);
        r3 += __shfl_down(r3, off);
        r4 += __shfl_down(r4, off);
    }
    const int wave = t >> 6, lane = t & 63;
    if (lane == 0) {
        red[wave][0] = r0; red[wave][1] = r1; red[wave][2] = r2;
        red[wave][3] = r3; red[wave][4] = r4;
    }
    __syncthreads();
    if (t == 0) {
        float* out = partials + (size_t)blockIdx.x * 5;
#pragma unroll
        for (int c = 0; c < 5; ++c)
            out[c] = red[0][c] + red[1][c];
    }
}

__global__ void finalize_kernel(const float* __restrict__ partials,
                                float* __restrict__ out)
{
    double l0 = 0, l1 = 0, l2 = 0, l3 = 0, l4 = 0;
    for (int b = threadIdx.x; b < NBLK; b += 64) {
        const float* p = partials + (size_t)b * 5;
        l0 += p[0]; l1 += p[1]; l2 += p[2]; l3 += p[3]; l4 += p[4];
    }
#pragma unroll
    for (int off = 32; off > 0; off >>= 1) {
        l0 += __shfl_down(l0, off);
        l1 += __shfl_down(l1, off);
        l2 += __shfl_down(l2, off);
        l3 += __shfl_down(l3, off);
        l4 += __shfl_down(l4, off);
    }
    if (threadIdx.x == 0) {
        const double num = l0 + l1 - 2.0 * l2;
        const double den = l0 + l3 - 2.0 * l4;
        out[0] = (float)(num / den);
    }
}

extern "C" void kernel_launch(void* const* d_in, const int* in_sizes, int n_in,
                              void* d_out, int out_size, void* d_ws, size_t ws_size,
                              hipStream_t stream)
{
    const float* depth1 = (const float*)d_in[0];
    const float* depth2 = (const float*)d_in[1];
    const float* pose   = (const float*)d_in[2];
    const float* img1   = (const float*)d_in[3];
    const float* img2   = (const float*)d_in[4];
    const float* poseg  = (const float*)d_in[5];

    float* partials = (float*)d_ws;   // NBLK*5 floats = ~58 KB

    pair_kernel<<<NBLK, BLOCK, 0, stream>>>(depth1, depth2, pose, img1, img2,
                                            poseg, partials);
    finalize_kernel<<<1, 64, 0, stream>>>(partials, (float*)d_out);
}

// Round 4
// 69.957 us; speedup vs baseline: 1.0529x; 1.0529x over previous
//
#include <hip/hip_runtime.h>

typedef float v2f __attribute__((ext_vector_type(2)));

constexpr int WIDTH  = 96;
constexpr int HEIGHT = 72;
constexpr int NPTS   = WIDTH * HEIGHT;   // 6912
constexpr int BLOCK  = 128;              // threads per block (2 waves)
constexpr int NTILE  = 256;              // n-points per block (2 per thread)
constexpr int MTILE  = 64;               // m-points per block
constexpr int NTB    = NPTS / NTILE;     // 27
constexpr int MTB    = NPTS / MTILE;     // 108
constexpr int NBLK   = NTB * MTB;        // 2916

// exp(-0.1*d) = exp2(d * KEXP)
constexpr float KEXP  = -0.14426950408889634f;  // -0.1 * log2(e)
constexpr float M2K   = -2.0f * KEXP;           // scale for a-side geometry

// Per-point record (SoA, P[k][NPTS]):
//  0..2  xyz1         3  K*|xyz1|^2
//  4..6  xyz2_t       7  K*|xyz2_t|^2
//  8..10 xyz2_gt     11  K*|xyz2_gt|^2
// 12..14 f1          15..17 f2
__global__ __launch_bounds__(256) void precompute_kernel(
    const float* __restrict__ depth1, const float* __restrict__ depth2,
    const float* __restrict__ pose,   const float* __restrict__ img1,
    const float* __restrict__ img2,   const float* __restrict__ poseg,
    float* __restrict__ P)
{
    const int idx = blockIdx.x * 256 + threadIdx.x;

    float R[12], G[12];
#pragma unroll
    for (int i = 0; i < 12; ++i) { R[i] = pose[i]; G[i] = poseg[i]; }

    const int u = idx % WIDTH;
    const int v = idx / WIDTH;
    const float gy = (float)u * (1.0f / 48.0f) - 1.0f;
    const float gz = (float)v * (1.0f / 36.0f) - 1.0f;
    const float d1 = depth1[idx];
    const float d2 = depth2[idx];
    const float x1 = d1, y1 = d1 * gy, z1 = d1 * gz;
    const float x2 = d2, y2 = d2 * gy, z2 = d2 * gz;
    const float xt = R[0] * x2 + R[1] * y2 + R[2]  * z2 + R[3];
    const float yt = R[4] * x2 + R[5] * y2 + R[6]  * z2 + R[7];
    const float zt = R[8] * x2 + R[9] * y2 + R[10] * z2 + R[11];
    const float xg = G[0] * x2 + G[1] * y2 + G[2]  * z2 + G[3];
    const float yg = G[4] * x2 + G[5] * y2 + G[6]  * z2 + G[7];
    const float zg = G[8] * x2 + G[9] * y2 + G[10] * z2 + G[11];

    float o[18];
    o[0] = x1; o[1] = y1; o[2]  = z1; o[3]  = KEXP * (x1*x1 + y1*y1 + z1*z1);
    o[4] = xt; o[5] = yt; o[6]  = zt; o[7]  = KEXP * (xt*xt + yt*yt + zt*zt);
    o[8] = xg; o[9] = yg; o[10] = zg; o[11] = KEXP * (xg*xg + yg*yg + zg*zg);
    o[12] = img1[idx];
    o[13] = img1[NPTS + idx];
    o[14] = img1[2 * NPTS + idx];
    o[15] = img2[idx];
    o[16] = img2[NPTS + idx];
    o[17] = img2[2 * NPTS + idx];

#pragma unroll
    for (int k = 0; k < 18; ++k) P[k * NPTS + idx] = o[k];
}

__global__ __launch_bounds__(BLOCK, 5) void pair_kernel(
    const float* __restrict__ P, float* __restrict__ partials)
{
    __shared__ float sm[MTILE][20];    // 80B rows, 16B-aligned
    __shared__ float red[2][5];

    const int t  = threadIdx.x;
    const int bn = blockIdx.x % NTB;
    const int bm = blockIdx.x / NTB;

    // stage m-tile into LDS (threads 0..MTILE-1; coalesced per-k loads)
    if (t < MTILE) {
        const int midx = bm * MTILE + t;
#pragma unroll
        for (int k = 0; k < 18; ++k) sm[t][k] = P[k * NPTS + midx];
    }

    // two n-points per thread, packed as v2f; coalesced per-k loads
    v2f A[18];
    {
        const int n0 = bn * NTILE + t;
#pragma unroll
        for (int k = 0; k < 18; ++k) {
            A[k].x = P[k * NPTS + n0];
            A[k].y = P[k * NPTS + n0 + BLOCK];
        }
#pragma unroll
        for (int grp = 0; grp < 3; ++grp) {
#pragma unroll
            for (int k = 0; k < 3; ++k) A[grp * 4 + k] *= M2K;
        }
    }

    __syncthreads();

    v2f s0 = {0.f, 0.f}, s1 = s0, s2 = s0, s3 = s0, s4 = s0;

#define COMPUTE(b)                                                         \
    do {                                                                   \
        v2f t11 = A[3] + (b)[3];                                           \
        t11 = A[0] * (b)[0] + t11;                                         \
        t11 = A[1] * (b)[1] + t11;                                         \
        t11 = A[2] * (b)[2] + t11;                                         \
        v2f t22 = A[7] + (b)[7];                                           \
        t22 = A[4] * (b)[4] + t22;                                         \
        t22 = A[5] * (b)[5] + t22;                                         \
        t22 = A[6] * (b)[6] + t22;                                         \
        v2f t12 = A[3] + (b)[7];                                           \
        t12 = A[0] * (b)[4] + t12;                                         \
        t12 = A[1] * (b)[5] + t12;                                         \
        t12 = A[2] * (b)[6] + t12;                                         \
        v2f tgg = A[11] + (b)[11];                                         \
        tgg = A[8]  * (b)[8]  + tgg;                                       \
        tgg = A[9]  * (b)[9]  + tgg;                                       \
        tgg = A[10] * (b)[10] + tgg;                                       \
        v2f t1g = A[3] + (b)[11];                                          \
        t1g = A[0] * (b)[8]  + t1g;                                        \
        t1g = A[1] * (b)[9]  + t1g;                                        \
        t1g = A[2] * (b)[10] + t1g;                                        \
        v2f g11 = A[12] * (b)[12];                                         \
        g11 = A[13] * (b)[13] + g11;                                       \
        g11 = A[14] * (b)[14] + g11;                                       \
        v2f g22 = A[15] * (b)[15];                                         \
        g22 = A[16] * (b)[16] + g22;                                       \
        g22 = A[17] * (b)[17] + g22;                                       \
        v2f g12 = A[12] * (b)[15];                                         \
        g12 = A[13] * (b)[16] + g12;                                       \
        g12 = A[14] * (b)[17] + g12;                                       \
        v2f e11, e22, e12, egg, e1g;                                       \
        e11.x = __builtin_amdgcn_exp2f(t11.x);                             \
        e11.y = __builtin_amdgcn_exp2f(t11.y);                             \
        e22.x = __builtin_amdgcn_exp2f(t22.x);                             \
        e22.y = __builtin_amdgcn_exp2f(t22.y);                             \
        e12.x = __builtin_amdgcn_exp2f(t12.x);                             \
        e12.y = __builtin_amdgcn_exp2f(t12.y);                             \
        egg.x = __builtin_amdgcn_exp2f(tgg.x);                             \
        egg.y = __builtin_amdgcn_exp2f(tgg.y);                             \
        e1g.x = __builtin_amdgcn_exp2f(t1g.x);                             \
        e1g.y = __builtin_amdgcn_exp2f(t1g.y);                             \
        s0 = e11 * g11 + s0;                                               \
        s1 = e22 * g22 + s1;                                               \
        s2 = e12 * g12 + s2;                                               \
        s3 = egg * g22 + s3;                                               \
        s4 = e1g * g12 + s4;                                               \
    } while (0)

    // 2-deep register pipeline over the m-tile
    float b0[18], b1[18];
#pragma unroll
    for (int k = 0; k < 18; ++k) b0[k] = sm[0][k];

    for (int m = 0; m < MTILE; m += 2) {
#pragma unroll
        for (int k = 0; k < 18; ++k) b1[k] = sm[m + 1][k];
        COMPUTE(b0);
#pragma unroll
        for (int k = 0; k < 18; ++k) b0[k] = sm[(m + 2) & (MTILE - 1)][k];
        COMPUTE(b1);
    }
#undef COMPUTE

    // per-thread fold then 64-lane reduction
    float r0 = s0.x + s0.y, r1 = s1.x + s1.y, r2 = s2.x + s2.y,
          r3 = s3.x + s3.y, r4 = s4.x + s4.y;
#pragma unroll
    for (int off = 32; off > 0; off >>= 1) {
        r0 += __shfl_down(r0, off);
        r1 += __shfl_down(r1, off);
        r2 += __shfl_down(r2, off);
        r3 += __shfl_down(r3, off);
        r4 += __shfl_down(r4, off);
    }
    const int wave = t >> 6, lane = t & 63;
    if (lane == 0) {
        red[wave][0] = r0; red[wave][1] = r1; red[wave][2] = r2;
        red[wave][3] = r3; red[wave][4] = r4;
    }
    __syncthreads();
    if (t == 0) {
        const float v0 = red[0][0] + red[1][0];
        const float v1 = red[0][1] + red[1][1];
        const float v2 = red[0][2] + red[1][2];
        const float v3 = red[0][3] + red[1][3];
        const float v4 = red[0][4] + red[1][4];
        partials[0 * NBLK + blockIdx.x] = v0;
        partials[1 * NBLK + blockIdx.x] = v1;
        partials[2 * NBLK + blockIdx.x] = v2;
        partials[3 * NBLK + blockIdx.x] = v3;
        partials[4 * NBLK + blockIdx.x] = v4;
    }
}

__global__ __launch_bounds__(256) void finalize_kernel(
    const float* __restrict__ partials, float* __restrict__ out)
{
    __shared__ double red[4][5];
    double l0 = 0, l1 = 0, l2 = 0, l3 = 0, l4 = 0;
    for (int b = threadIdx.x; b < NBLK; b += 256) {
        l0 += partials[0 * NBLK + b];
        l1 += partials[1 * NBLK + b];
        l2 += partials[2 * NBLK + b];
        l3 += partials[3 * NBLK + b];
        l4 += partials[4 * NBLK + b];
    }
#pragma unroll
    for (int off = 32; off > 0; off >>= 1) {
        l0 += __shfl_down(l0, off);
        l1 += __shfl_down(l1, off);
        l2 += __shfl_down(l2, off);
        l3 += __shfl_down(l3, off);
        l4 += __shfl_down(l4, off);
    }
    const int wave = threadIdx.x >> 6, lane = threadIdx.x & 63;
    if (lane == 0) {
        red[wave][0] = l0; red[wave][1] = l1; red[wave][2] = l2;
        red[wave][3] = l3; red[wave][4] = l4;
    }
    __syncthreads();
    if (threadIdx.x == 0) {
        const double a0 = red[0][0] + red[1][0] + red[2][0] + red[3][0];
        const double a1 = red[0][1] + red[1][1] + red[2][1] + red[3][1];
        const double a2 = red[0][2] + red[1][2] + red[2][2] + red[3][2];
        const double a3 = red[0][3] + red[1][3] + red[2][3] + red[3][3];
        const double a4 = red[0][4] + red[1][4] + red[2][4] + red[3][4];
        const double num = a0 + a1 - 2.0 * a2;
        const double den = a0 + a3 - 2.0 * a4;
        out[0] = (float)(num / den);
    }
}

extern "C" void kernel_launch(void* const* d_in, const int* in_sizes, int n_in,
                              void* d_out, int out_size, void* d_ws, size_t ws_size,
                              hipStream_t stream)
{
    const float* depth1 = (const float*)d_in[0];
    const float* depth2 = (const float*)d_in[1];
    const float* pose   = (const float*)d_in[2];
    const float* img1   = (const float*)d_in[3];
    const float* img2   = (const float*)d_in[4];
    const float* poseg  = (const float*)d_in[5];

    float* P        = (float*)d_ws;                 // 18*6912 floats = 498 KB
    float* partials = P + 18 * NPTS;                // 5*2916 floats  =  58 KB

    precompute_kernel<<<NPTS / 256, 256, 0, stream>>>(depth1, depth2, pose,
                                                      img1, img2, poseg, P);
    pair_kernel<<<NBLK, BLOCK, 0, stream>>>(P, partials);
    finalize_kernel<<<1, 256, 0, stream>>>(partials, (float*)d_out);
}

// Round 5
// 59.590 us; speedup vs baseline: 1.2360x; 1.1740x over previous
//
#include <hip/hip_runtime.h>

typedef float v2f __attribute__((ext_vector_type(2)));

constexpr int WIDTH  = 96;
constexpr int HEIGHT = 72;
constexpr int NPTS   = WIDTH * HEIGHT;   // 6912
constexpr int BLOCK  = 128;              // threads per block (2 waves)
constexpr int NTILE  = 256;              // n-points per block (2 per thread)
constexpr int MTILE  = 64;               // m-points per block chunk
constexpr int NTB    = NPTS / NTILE;     // 27
constexpr int MTB    = NPTS / MTILE;     // 108
constexpr int NBLK   = NTB * MTB;        // 2916
constexpr int ROWF   = 20;               // floats per padded AoS row (80 B)

// exp(-0.1*d) = exp2(d * KEXP)
constexpr float KEXP  = -0.14426950408889634f;  // -0.1 * log2(e)
constexpr float M2K   = -2.0f * KEXP;           // scale for a-side geometry

// Per-point AoS record Q[idx][20]:
//  0..2  xyz1         3  K*|xyz1|^2
//  4..6  xyz2_t       7  K*|xyz2_t|^2
//  8..10 xyz2_gt     11  K*|xyz2_gt|^2
// 12..14 f1          15..17 f2     18..19 pad
__global__ __launch_bounds__(256) void precompute_kernel(
    const float* __restrict__ depth1, const float* __restrict__ depth2,
    const float* __restrict__ pose,   const float* __restrict__ img1,
    const float* __restrict__ img2,   const float* __restrict__ poseg,
    float* __restrict__ Q)
{
    const int idx = blockIdx.x * 256 + threadIdx.x;

    float R[12], G[12];
#pragma unroll
    for (int i = 0; i < 12; ++i) { R[i] = pose[i]; G[i] = poseg[i]; }

    const int u = idx % WIDTH;
    const int v = idx / WIDTH;
    const float gy = (float)u * (1.0f / 48.0f) - 1.0f;
    const float gz = (float)v * (1.0f / 36.0f) - 1.0f;
    const float d1 = depth1[idx];
    const float d2 = depth2[idx];
    const float x1 = d1, y1 = d1 * gy, z1 = d1 * gz;
    const float x2 = d2, y2 = d2 * gy, z2 = d2 * gz;
    const float xt = R[0] * x2 + R[1] * y2 + R[2]  * z2 + R[3];
    const float yt = R[4] * x2 + R[5] * y2 + R[6]  * z2 + R[7];
    const float zt = R[8] * x2 + R[9] * y2 + R[10] * z2 + R[11];
    const float xg = G[0] * x2 + G[1] * y2 + G[2]  * z2 + G[3];
    const float yg = G[4] * x2 + G[5] * y2 + G[6]  * z2 + G[7];
    const float zg = G[8] * x2 + G[9] * y2 + G[10] * z2 + G[11];

    float o[ROWF];
    o[0] = x1; o[1] = y1; o[2]  = z1; o[3]  = KEXP * (x1*x1 + y1*y1 + z1*z1);
    o[4] = xt; o[5] = yt; o[6]  = zt; o[7]  = KEXP * (xt*xt + yt*yt + zt*zt);
    o[8] = xg; o[9] = yg; o[10] = zg; o[11] = KEXP * (xg*xg + yg*yg + zg*zg);
    o[12] = img1[idx];
    o[13] = img1[NPTS + idx];
    o[14] = img1[2 * NPTS + idx];
    o[15] = img2[idx];
    o[16] = img2[NPTS + idx];
    o[17] = img2[2 * NPTS + idx];
    o[18] = 0.f; o[19] = 0.f;

    float4* row = (float4*)(Q + (size_t)idx * ROWF);
#pragma unroll
    for (int k = 0; k < 5; ++k)
        row[k] = make_float4(o[4 * k], o[4 * k + 1], o[4 * k + 2], o[4 * k + 3]);
}

__global__ __launch_bounds__(BLOCK) void pair_kernel(
    const float* __restrict__ Q, float* __restrict__ partials)
{
    __shared__ float red[2][5];

    const int t  = threadIdx.x;
    const int bn = blockIdx.x % NTB;
    const int bm = blockIdx.x / NTB;

    // two n-points per thread, packed as v2f; a-side geometry pre-scaled by -2K
    v2f A[18];
    {
        const int n0 = bn * NTILE + t;
        const float4* r0 = (const float4*)(Q + (size_t)n0 * ROWF);
        const float4* r1 = (const float4*)(Q + (size_t)(n0 + BLOCK) * ROWF);
#pragma unroll
        for (int k = 0; k < 5; ++k) {
            const float4 a0 = r0[k];
            const float4 a1 = r1[k];
            if (4 * k < 18)     { A[4 * k].x     = a0.x; A[4 * k].y     = a1.x; }
            if (4 * k + 1 < 18) { A[4 * k + 1].x = a0.y; A[4 * k + 1].y = a1.y; }
            if (4 * k + 2 < 18) { A[4 * k + 2].x = a0.z; A[4 * k + 2].y = a1.z; }
            if (4 * k + 3 < 18) { A[4 * k + 3].x = a0.w; A[4 * k + 3].y = a1.w; }
        }
#pragma unroll
        for (int grp = 0; grp < 3; ++grp) {
#pragma unroll
            for (int k = 0; k < 3; ++k) A[grp * 4 + k] *= M2K;
        }
    }

    v2f s0 = {0.f, 0.f}, s1 = s0, s2 = s0, s3 = s0, s4 = s0;

#define COMPUTE(b)                                                         \
    do {                                                                   \
        v2f t11 = A[3] + (b)[3];                                           \
        t11 = A[0] * (b)[0] + t11;                                         \
        t11 = A[1] * (b)[1] + t11;                                         \
        t11 = A[2] * (b)[2] + t11;                                         \
        v2f t22 = A[7] + (b)[7];                                           \
        t22 = A[4] * (b)[4] + t22;                                         \
        t22 = A[5] * (b)[5] + t22;                                         \
        t22 = A[6] * (b)[6] + t22;                                         \
        v2f t12 = A[3] + (b)[7];                                           \
        t12 = A[0] * (b)[4] + t12;                                         \
        t12 = A[1] * (b)[5] + t12;                                         \
        t12 = A[2] * (b)[6] + t12;                                         \
        v2f tgg = A[11] + (b)[11];                                         \
        tgg = A[8]  * (b)[8]  + tgg;                                       \
        tgg = A[9]  * (b)[9]  + tgg;                                       \
        tgg = A[10] * (b)[10] + tgg;                                       \
        v2f t1g = A[3] + (b)[11];                                          \
        t1g = A[0] * (b)[8]  + t1g;                                        \
        t1g = A[1] * (b)[9]  + t1g;                                        \
        t1g = A[2] * (b)[10] + t1g;                                        \
        v2f g11 = A[12] * (b)[12];                                         \
        g11 = A[13] * (b)[13] + g11;                                       \
        g11 = A[14] * (b)[14] + g11;                                       \
        v2f g22 = A[15] * (b)[15];                                         \
        g22 = A[16] * (b)[16] + g22;                                       \
        g22 = A[17] * (b)[17] + g22;                                       \
        v2f g12 = A[12] * (b)[15];                                         \
        g12 = A[13] * (b)[16] + g12;                                       \
        g12 = A[14] * (b)[17] + g12;                                       \
        v2f e11, e22, e12, egg, e1g;                                       \
        e11.x = __builtin_amdgcn_exp2f(t11.x);                             \
        e11.y = __builtin_amdgcn_exp2f(t11.y);                             \
        e22.x = __builtin_amdgcn_exp2f(t22.x);                             \
        e22.y = __builtin_amdgcn_exp2f(t22.y);                             \
        e12.x = __builtin_amdgcn_exp2f(t12.x);                             \
        e12.y = __builtin_amdgcn_exp2f(t12.y);                             \
        egg.x = __builtin_amdgcn_exp2f(tgg.x);                             \
        egg.y = __builtin_amdgcn_exp2f(tgg.y);                             \
        e1g.x = __builtin_amdgcn_exp2f(t1g.x);                             \
        e1g.y = __builtin_amdgcn_exp2f(t1g.y);                             \
        s0 = e11 * g11 + s0;                                               \
        s1 = e22 * g22 + s1;                                               \
        s2 = e12 * g12 + s2;                                               \
        s3 = egg * g22 + s3;                                               \
        s4 = e1g * g12 + s4;                                               \
    } while (0)

    // b-rows streamed with wave-uniform addresses -> scalar (SMEM) loads.
    // 2-deep register rotation hides the SMEM latency.
    const float* __restrict__ q = Q + (size_t)(bm * MTILE) * ROWF;
    float b0[18], b1[18];
#pragma unroll
    for (int k = 0; k < 18; ++k) b0[k] = q[k];

    for (int m = 0; m < MTILE; m += 2) {
#pragma unroll
        for (int k = 0; k < 18; ++k) b1[k] = q[(m + 1) * ROWF + k];
        COMPUTE(b0);
#pragma unroll
        for (int k = 0; k < 18; ++k) b0[k] = q[((m + 2) & (MTILE - 1)) * ROWF + k];
        COMPUTE(b1);
    }
#undef COMPUTE

    // per-thread fold then 64-lane reduction
    float r0 = s0.x + s0.y, r1 = s1.x + s1.y, r2 = s2.x + s2.y,
          r3 = s3.x + s3.y, r4 = s4.x + s4.y;
#pragma unroll
    for (int off = 32; off > 0; off >>= 1) {
        r0 += __shfl_down(r0, off);
        r1 += __shfl_down(r1, off);
        r2 += __shfl_down(r2, off);
        r3 += __shfl_down(r3, off);
        r4 += __shfl_down(r4, off);
    }
    const int wave = t >> 6, lane = t & 63;
    if (lane == 0) {
        red[wave][0] = r0; red[wave][1] = r1; red[wave][2] = r2;
        red[wave][3] = r3; red[wave][4] = r4;
    }
    __syncthreads();
    if (t == 0) {
        partials[0 * NBLK + blockIdx.x] = red[0][0] + red[1][0];
        partials[1 * NBLK + blockIdx.x] = red[0][1] + red[1][1];
        partials[2 * NBLK + blockIdx.x] = red[0][2] + red[1][2];
        partials[3 * NBLK + blockIdx.x] = red[0][3] + red[1][3];
        partials[4 * NBLK + blockIdx.x] = red[0][4] + red[1][4];
    }
}

__global__ __launch_bounds__(256) void finalize_kernel(
    const float* __restrict__ partials, float* __restrict__ out)
{
    __shared__ double red[4][5];
    double l0 = 0, l1 = 0, l2 = 0, l3 = 0, l4 = 0;
    for (int b = threadIdx.x; b < NBLK; b += 256) {
        l0 += partials[0 * NBLK + b];
        l1 += partials[1 * NBLK + b];
        l2 += partials[2 * NBLK + b];
        l3 += partials[3 * NBLK + b];
        l4 += partials[4 * NBLK + b];
    }
#pragma unroll
    for (int off = 32; off > 0; off >>= 1) {
        l0 += __shfl_down(l0, off);
        l1 += __shfl_down(l1, off);
        l2 += __shfl_down(l2, off);
        l3 += __shfl_down(l3, off);
        l4 += __shfl_down(l4, off);
    }
    const int wave = threadIdx.x >> 6, lane = threadIdx.x & 63;
    if (lane == 0) {
        red[wave][0] = l0; red[wave][1] = l1; red[wave][2] = l2;
        red[wave][3] = l3; red[wave][4] = l4;
    }
    __syncthreads();
    if (threadIdx.x == 0) {
        const double a0 = red[0][0] + red[1][0] + red[2][0] + red[3][0];
        const double a1 = red[0][1] + red[1][1] + red[2][1] + red[3][1];
        const double a2 = red[0][2] + red[1][2] + red[2][2] + red[3][2];
        const double a3 = red[0][3] + red[1][3] + red[2][3] + red[3][3];
        const double a4 = red[0][4] + red[1][4] + red[2][4] + red[3][4];
        const double num = a0 + a1 - 2.0 * a2;
        const double den = a0 + a3 - 2.0 * a4;
        out[0] = (float)(num / den);
    }
}

extern "C" void kernel_launch(void* const* d_in, const int* in_sizes, int n_in,
                              void* d_out, int out_size, void* d_ws, size_t ws_size,
                              hipStream_t stream)
{
    const float* depth1 = (const float*)d_in[0];
    const float* depth2 = (const float*)d_in[1];
    const float* pose   = (const float*)d_in[2];
    const float* img1   = (const float*)d_in[3];
    const float* img2   = (const float*)d_in[4];
    const float* poseg  = (const float*)d_in[5];

    float* Q        = (float*)d_ws;                 // 6912*20 floats = 540 KB
    float* partials = Q + (size_t)NPTS * ROWF;      // 5*2916 floats  =  58 KB

    precompute_kernel<<<NPTS / 256, 256, 0, stream>>>(depth1, depth2, pose,
                                                      img1, img2, poseg, Q);
    pair_kernel<<<NBLK, BLOCK, 0, stream>>>(Q, partials);
    finalize_kernel<<<1, 256, 0, stream>>>(partials, (float*)d_out);
}